// Round 8
// baseline (260.851 us; speedup 1.0000x reference)
//
#include <hip/hip_runtime.h>
#include <hip/hip_bf16.h>

// Problem shapes (fixed by setup_inputs)
constexpr int B_  = 4;
constexpr int N_  = 2048;
constexpr int C_  = 1024;
constexpr int H_  = 16;
constexpr int HD  = 64;    // head dim
constexpr int LR  = 20;    // low rank
constexpr int RS  = 200;   // subsample length R
constexpr int RP  = 224;   // RS padded to multiple of 32 (zero-filled)
constexpr int XS  = 232;   // LDS row stride for prep (16B-aligned, 2-way banks)

typedef __attribute__((ext_vector_type(8))) short bf16x8;
typedef __attribute__((ext_vector_type(4))) float f32x4;

__device__ __forceinline__ float b2f_raw(unsigned short u) {
    union { unsigned int i; float f; } v;
    v.i = ((unsigned int)u) << 16;
    return v.f;
}
__device__ __forceinline__ unsigned short f2b(float f) {
    __hip_bfloat16 h = __float2bfloat16(f);
    return *(unsigned short*)&h;
}

// async 16B global->LDS (wave-uniform LDS base; HW scatters lane i at +16*i)
__device__ __forceinline__ void async_load16(const unsigned short* g, unsigned short* l) {
    __builtin_amdgcn_global_load_lds(
        (const __attribute__((address_space(1))) unsigned int*)(const void*)g,
        (__attribute__((address_space(3))) unsigned int*)(void*)l,
        16, 0, 0);
}

// ---------------------------------------------------------------------------
// In-block dtype detection (replaces the serial 1-block detect kernel).
// Low 16 bits of fp32 words = uniform mantissa bits (~15% in exponent range
// [103,140]); of packed bf16 pairs = real bf16 sample (~100% in range).
// Reads the first 4KB of x (L2-hot). Requires blockDim.x == 256.
// Returns 1 = bf16 inputs, 0 = fp32. Ends with __syncthreads().
// ---------------------------------------------------------------------------
__device__ __forceinline__ int block_detect_flag(const unsigned int* __restrict__ xw,
                                                 int* s /* shared[256] */) {
    const int t = threadIdx.x;
    int cnt = 0;
    #pragma unroll
    for (int i = 0; i < 4; ++i) {
        const unsigned int w = xw[t * 4 + i];
        const unsigned int e = (w >> 7) & 0xFFu;
        cnt += (e >= 103u && e <= 140u) ? 1 : 0;
    }
    s[t] = cnt;
    __syncthreads();
    for (int off = 128; off > 0; off >>= 1) {
        if (t < off) s[t] += s[t + off];
        __syncthreads();
    }
    const int flag = (s[0] > 512) ? 1 : 0;
    __syncthreads();   // protect s before any reuse
    return flag;
}

// ---------------------------------------------------------------------------
// Convert all 8 inputs to bf16 copies in ws. blockIdx.y selects buffer.
// Self-detects dtype (no separate detect kernel / global flag).
// ---------------------------------------------------------------------------
struct CvtArgs {
    const void* src[8];
    unsigned short* dst[8];
    int size[8];
};

__global__ __launch_bounds__(256)
void convert_kernel(CvtArgs args) {
    __shared__ int s[256];
    const bool isbf = (block_detect_flag((const unsigned int*)args.src[0], s) != 0);

    const int buf = blockIdx.y;
    const int n4 = args.size[buf] >> 2;
    const int stride = gridDim.x * blockDim.x;
    for (int i = blockIdx.x * blockDim.x + threadIdx.x; i < n4; i += stride) {
        ushort4 o;
        if (isbf) {
            o = ((const ushort4*)args.src[buf])[i];
        } else {
            const float4 v = ((const float4*)args.src[buf])[i];
            o.x = f2b(v.x); o.y = f2b(v.y); o.z = f2b(v.z); o.w = f2b(v.w);
        }
        ((ushort4*)args.dst[buf])[i] = o;
    }
}

// ---------------------------------------------------------------------------
// prep_kernel: one block per (b,h). Replaces wec + gather + collapse.
//  LDS xhs[din][r]:  x[b, idx[r], h*64+din], r<200, zero-pad to 224
//  LDS wcs[dout][r]: sum_e w[h,r,e]*cw_w[dout, sel*20+e]  (sel=0: we, 1: wr)
//  We2T[bh][dout][din] = sum_r wcs[dout][r] * xhs[din][r]  (MFMA, K=224)
// idx[r] = (r*(N-1))/(R-1) exactly (trunc linspace).
// Phases: gather+wec(0) | waves0,1 MFMA->we2t | wec(1) | waves2,3 ->wr2t.
// ---------------------------------------------------------------------------
__device__ __forceinline__ void prep_fill_wcs(unsigned short* wcs,
                                              const unsigned short* __restrict__ w_in,
                                              const unsigned short* __restrict__ cwwb,
                                              int h, int sel) {
    for (int o = threadIdx.x; o < HD * RP; o += 256) {
        const int dout = o & 63;
        const int r    = o >> 6;
        float s = 0.f;
        if (r < RS) {
            #pragma unroll
            for (int e = 0; e < LR; ++e)
                s += b2f_raw(w_in[((size_t)h * RS + r) * LR + e]) *
                     b2f_raw(cwwb[dout * 2 * LR + sel * LR + e]);
        }
        wcs[dout * XS + r] = f2b(s);
    }
}

__device__ __forceinline__ void prep_collapse_job(const unsigned short* wcs,
                                                  const unsigned short* xhs,
                                                  unsigned short* __restrict__ dst,
                                                  int dh, int lane) {
    const int lq = lane >> 4;
    const int lm = lane & 15;
    f32x4 acc[2][4];
    #pragma unroll
    for (int i = 0; i < 2; ++i)
        #pragma unroll
        for (int j = 0; j < 4; ++j) acc[i][j] = 0.f;

    for (int ks = 0; ks < RP / 32; ++ks) {
        bf16x8 a[2], bfr[4];
        #pragma unroll
        for (int rt = 0; rt < 2; ++rt)
            a[rt] = *(const bf16x8*)&wcs[(dh * 32 + rt * 16 + lm) * XS + ks * 32 + lq * 8];
        #pragma unroll
        for (int j = 0; j < 4; ++j)
            bfr[j] = *(const bf16x8*)&xhs[(j * 16 + lm) * XS + ks * 32 + lq * 8];
        #pragma unroll
        for (int rt = 0; rt < 2; ++rt)
            #pragma unroll
            for (int j = 0; j < 4; ++j)
                acc[rt][j] = __builtin_amdgcn_mfma_f32_16x16x32_bf16(
                    a[rt], bfr[j], acc[rt][j], 0, 0, 0);
    }

    // C-layout: col(din)=j*16+lm, row-in-tile=lq*4+r
    #pragma unroll
    for (int rt = 0; rt < 2; ++rt)
        #pragma unroll
        for (int j = 0; j < 4; ++j)
            #pragma unroll
            for (int r = 0; r < 4; ++r) {
                const int dout = dh * 32 + rt * 16 + lq * 4 + r;
                const int din  = j * 16 + lm;
                dst[dout * HD + din] = f2b(acc[rt][j][r]);
            }
}

__global__ __launch_bounds__(256)
void prep_kernel(const unsigned short* __restrict__ xb,
                 const unsigned short* __restrict__ we_in,
                 const unsigned short* __restrict__ wr_in,
                 const unsigned short* __restrict__ cwwb,
                 unsigned short* __restrict__ we2t,
                 unsigned short* __restrict__ wr2t) {
    __shared__ __align__(16) unsigned short xhs[HD * XS];  // 29 KB
    __shared__ __align__(16) unsigned short wcs[HD * XS];  // 29 KB

    const int bh = blockIdx.x;
    const int b  = bh >> 4;
    const int h  = bh & 15;
    const int wave = threadIdx.x >> 6;
    const int lane = threadIdx.x & 63;

    // phase 0: gather xh + wec(sel=0)
    for (int o = threadIdx.x; o < HD * RP; o += 256) {
        const int din = o & 63;   // consecutive threads -> coalesced 128B reads
        const int r   = o >> 6;
        unsigned short v = 0;
        if (r < RS) {
            const int ir = (r * (N_ - 1)) / (RS - 1);
            v = xb[((size_t)b * N_ + ir) * C_ + h * HD + din];
        }
        xhs[din * XS + r] = v;
    }
    prep_fill_wcs(wcs, we_in, cwwb, h, 0);
    __syncthreads();

    // phase 1: waves 0,1 -> We2T halves
    if (wave < 2)
        prep_collapse_job(wcs, xhs, we2t + (size_t)bh * HD * HD, wave, lane);
    __syncthreads();

    // phase 2: wec(sel=1)
    prep_fill_wcs(wcs, wr_in, cwwb, h, 1);
    __syncthreads();

    // phase 3: waves 2,3 -> Wr2T halves
    if (wave >= 2)
        prep_collapse_job(wcs, xhs, wr2t + (size_t)bh * HD * HD, wave - 2, lane);
}

// ---------------------------------------------------------------------------
// Fused gemm1 + l2norm + score + cw projection.
// Grid (H, M/128). Block 256 = 4 waves. Block computes, for head h and rows
// [m0, m0+128): q = x@qk_w[h*64..+64]^T and k = x@qk_w[C+h*64..+64]^T
// (128x128 MFMA tile, BK=32, async LDS staging), then per-row l2 norms,
// scaled qn/kn -> LDS, then attn = qn@We2T^T + kn@Wr2T^T + cw_b -> global.
// ---------------------------------------------------------------------------
__global__ __launch_bounds__(256)
void gemm1_score_kernel(const unsigned short* __restrict__ xb,
                        const unsigned short* __restrict__ qkwb,
                        const unsigned short* __restrict__ we2t,
                        const unsigned short* __restrict__ wr2t,
                        const unsigned short* __restrict__ cwbb,
                        unsigned short* __restrict__ attn) {
    constexpr int BK = 32;
    constexpr int QS = 72;   // qn/kn row stride (16B-aligned, bank-spread)
    __shared__ __align__(16) unsigned short pool[2 * 128 * QS];  // 36 KB
    unsigned short* As = pool;               // 128*32 (phase 1)
    unsigned short* Bs = pool + 4096;        // 128*32 (phase 1)
    unsigned short* qn = pool;               // 128*QS (phase 2)
    unsigned short* kn = pool + 128 * QS;    // 128*QS (phase 2)

    const int t    = threadIdx.x;
    const int wave = t >> 6;
    const int lane = t & 63;
    const int h    = blockIdx.x;
    const int m0   = blockIdx.y * 128;
    const int K    = C_;

    const int srow = lane >> 2;
    const int scol = (lane & 3) * 8;
    const unsigned short* ga0 = xb + (size_t)(m0 + wave * 16 + srow) * K + scol;
    const unsigned short* ga1 = xb + (size_t)(m0 + (wave + 4) * 16 + srow) * K + scol;
    const unsigned short* gb0 = qkwb + (size_t)(h * HD + wave * 16 + srow) * K + scol;
    const unsigned short* gb1 = qkwb + (size_t)(C_ + h * HD + wave * 16 + srow) * K + scol;
    unsigned short* lA0 = &As[wave * 512];
    unsigned short* lA1 = &As[(wave + 4) * 512];
    unsigned short* lB0 = &Bs[wave * 512];
    unsigned short* lB1 = &Bs[(wave + 4) * 512];

    const int wr = (wave >> 1) * 64;        // row quadrant
    const int wc = (wave & 1) * 64;         // col quadrant: 0 = q, 64 = k
    const int lq = lane >> 4;
    const int lm = lane & 15;

    f32x4 acc[4][4];
    #pragma unroll
    for (int i = 0; i < 4; ++i)
        #pragma unroll
        for (int j = 0; j < 4; ++j) acc[i][j] = 0.f;

    for (int k0 = 0; k0 < K; k0 += BK) {
        async_load16(ga0, lA0);
        async_load16(ga1, lA1);
        async_load16(gb0, lB0);
        async_load16(gb1, lB1);
        ga0 += BK; ga1 += BK; gb0 += BK; gb1 += BK;
        __syncthreads();

        bf16x8 af[4], bfr[4];
        #pragma unroll
        for (int i = 0; i < 4; ++i)
            af[i] = *(const bf16x8*)&As[(wr + i * 16 + lm) * BK + lq * 8];
        #pragma unroll
        for (int j = 0; j < 4; ++j)
            bfr[j] = *(const bf16x8*)&Bs[(wc + j * 16 + lm) * BK + lq * 8];

        #pragma unroll
        for (int i = 0; i < 4; ++i)
            #pragma unroll
            for (int j = 0; j < 4; ++j)
                acc[i][j] = __builtin_amdgcn_mfma_f32_16x16x32_bf16(
                    af[i], bfr[j], acc[i][j], 0, 0, 0);

        __syncthreads();   // also guards pool reuse below after last iter
    }

    // ---- phase 2a: per-row l2 norm + scaled bf16 store to LDS ----
    unsigned short* dst = (wc == 0) ? qn : kn;
    #pragma unroll
    for (int i = 0; i < 4; ++i) {
        float inv[4];
        #pragma unroll
        for (int r = 0; r < 4; ++r) {
            float s = 0.f;
            #pragma unroll
            for (int j = 0; j < 4; ++j) s += acc[i][j][r] * acc[i][j][r];
            s += __shfl_xor(s, 1, 64);
            s += __shfl_xor(s, 2, 64);
            s += __shfl_xor(s, 4, 64);
            s += __shfl_xor(s, 8, 64);
            inv[r] = 1.f / fmaxf(sqrtf(s), 1e-12f);
        }
        #pragma unroll
        for (int j = 0; j < 4; ++j)
            #pragma unroll
            for (int r = 0; r < 4; ++r) {
                const int row = wr + i * 16 + lq * 4 + r;
                dst[row * QS + j * 16 + lm] = f2b(acc[i][j][r] * inv[r]);
            }
    }
    __syncthreads();

    // ---- phase 2b: attn = qn@We2T^T + kn@Wr2T^T + cw_b ----
    const int b  = blockIdx.y >> 4;          // 16 row-blocks per batch
    const int bh = b * H_ + h;
    const unsigned short* wq = we2t + (size_t)bh * HD * HD;
    const unsigned short* wk = wr2t + (size_t)bh * HD * HD;

    bf16x8 bq[2][4], bk[2][4];
    #pragma unroll
    for (int t2 = 0; t2 < 2; ++t2)
        #pragma unroll
        for (int j = 0; j < 4; ++j) {
            const int dout = j * 16 + lm;
            bq[t2][j] = *(const bf16x8*)&wq[dout * HD + t2 * 32 + lq * 8];
            bk[t2][j] = *(const bf16x8*)&wk[dout * HD + t2 * 32 + lq * 8];
        }

    f32x4 accS[2][4];
    #pragma unroll
    for (int rt = 0; rt < 2; ++rt)
        #pragma unroll
        for (int j = 0; j < 4; ++j) accS[rt][j] = 0.f;

    #pragma unroll
    for (int rt = 0; rt < 2; ++rt) {
        const int lr = wave * 32 + rt * 16 + lm;   // local row, A-layout
        bf16x8 aq0 = *(const bf16x8*)&qn[lr * QS + lq * 8];
        bf16x8 aq1 = *(const bf16x8*)&qn[lr * QS + 32 + lq * 8];
        bf16x8 ak0 = *(const bf16x8*)&kn[lr * QS + lq * 8];
        bf16x8 ak1 = *(const bf16x8*)&kn[lr * QS + 32 + lq * 8];
        #pragma unroll
        for (int j = 0; j < 4; ++j) {
            accS[rt][j] = __builtin_amdgcn_mfma_f32_16x16x32_bf16(aq0, bq[0][j], accS[rt][j], 0, 0, 0);
            accS[rt][j] = __builtin_amdgcn_mfma_f32_16x16x32_bf16(aq1, bq[1][j], accS[rt][j], 0, 0, 0);
            accS[rt][j] = __builtin_amdgcn_mfma_f32_16x16x32_bf16(ak0, bk[0][j], accS[rt][j], 0, 0, 0);
            accS[rt][j] = __builtin_amdgcn_mfma_f32_16x16x32_bf16(ak1, bk[1][j], accS[rt][j], 0, 0, 0);
        }
    }

    #pragma unroll
    for (int rt = 0; rt < 2; ++rt)
        #pragma unroll
        for (int j = 0; j < 4; ++j) {
            const int dout = j * 16 + lm;
            const float bv = b2f_raw(cwbb[dout]);
            #pragma unroll
            for (int r = 0; r < 4; ++r) {
                const int row = m0 + wave * 32 + rt * 16 + lq * 4 + r;
                attn[(size_t)row * C_ + h * HD + dout] = f2b(accS[rt][j][r] + bv);
            }
        }
}

// ---------------------------------------------------------------------------
// MFMA GEMM (NT) for the output projection. 128x128 tile, BK=32.
// Self-detects output dtype from x.
// ---------------------------------------------------------------------------
template <bool OBF>
__device__ void mfma_gemm_body(const unsigned short* __restrict__ A,
                               const unsigned short* __restrict__ W,
                               const unsigned short* __restrict__ bias,
                               void* __restrict__ out,
                               int M, int N, int K) {
    constexpr int BM = 128, BN = 128, BK = 32;
    __shared__ __align__(16) unsigned short As[BM * BK];
    __shared__ __align__(16) unsigned short Bs[BN * BK];

    const int t    = threadIdx.x;
    const int wave = t >> 6;
    const int lane = t & 63;
    const int m0   = blockIdx.y * BM;
    const int n0   = blockIdx.x * BN;

    const int srow = lane >> 2;
    const int scol = (lane & 3) * 8;
    const unsigned short* ga0 = A + (size_t)(m0 + wave * 16 + srow) * K + scol;
    const unsigned short* ga1 = A + (size_t)(m0 + (wave + 4) * 16 + srow) * K + scol;
    const unsigned short* gb0 = W + (size_t)(n0 + wave * 16 + srow) * K + scol;
    const unsigned short* gb1 = W + (size_t)(n0 + (wave + 4) * 16 + srow) * K + scol;
    unsigned short* lA0 = &As[wave * 512];
    unsigned short* lA1 = &As[(wave + 4) * 512];
    unsigned short* lB0 = &Bs[wave * 512];
    unsigned short* lB1 = &Bs[(wave + 4) * 512];

    const int wr = (wave >> 1) * 64;
    const int wc = (wave & 1) * 64;
    const int lq = lane >> 4;
    const int lm = lane & 15;

    f32x4 acc[4][4];
    #pragma unroll
    for (int i = 0; i < 4; ++i)
        #pragma unroll
        for (int j = 0; j < 4; ++j) acc[i][j] = 0.f;

    for (int k0 = 0; k0 < K; k0 += BK) {
        async_load16(ga0, lA0);
        async_load16(ga1, lA1);
        async_load16(gb0, lB0);
        async_load16(gb1, lB1);
        ga0 += BK; ga1 += BK; gb0 += BK; gb1 += BK;
        __syncthreads();

        bf16x8 af[4], bfr[4];
        #pragma unroll
        for (int i = 0; i < 4; ++i)
            af[i] = *(const bf16x8*)&As[(wr + i * 16 + lm) * BK + lq * 8];
        #pragma unroll
        for (int j = 0; j < 4; ++j)
            bfr[j] = *(const bf16x8*)&Bs[(wc + j * 16 + lm) * BK + lq * 8];

        #pragma unroll
        for (int i = 0; i < 4; ++i)
            #pragma unroll
            for (int j = 0; j < 4; ++j)
                acc[i][j] = __builtin_amdgcn_mfma_f32_16x16x32_bf16(
                    af[i], bfr[j], acc[i][j], 0, 0, 0);

        __syncthreads();
    }

    #pragma unroll
    for (int i = 0; i < 4; ++i) {
        #pragma unroll
        for (int j = 0; j < 4; ++j) {
            const int col = n0 + wc + j * 16 + lm;
            const float bv = b2f_raw(bias[col]);
            #pragma unroll
            for (int r = 0; r < 4; ++r) {
                const int row = m0 + wr + i * 16 + lq * 4 + r;
                const float v = acc[i][j][r] + bv;
                if constexpr (OBF)
                    ((__hip_bfloat16*)out)[(size_t)row * N + col] = __float2bfloat16(v);
                else
                    ((float*)out)[(size_t)row * N + col] = v;
            }
        }
    }
}

__global__ __launch_bounds__(256)
void gemm2_kernel(const unsigned int* __restrict__ x_raw,
                  const unsigned short* __restrict__ attn,
                  const unsigned short* __restrict__ pwb,
                  const unsigned short* __restrict__ pbb,
                  void* __restrict__ out) {
    __shared__ int s[256];
    const int isbf = block_detect_flag(x_raw, s);
    if (isbf) mfma_gemm_body<true>(attn, pwb, pbb, out, B_ * N_, C_, C_);
    else      mfma_gemm_body<false>(attn, pwb, pbb, out, B_ * N_, C_, C_);
}

// ---------------------------------------------------------------------------
// 4 dispatches: convert -> prep -> gemm1_score -> gemm2.
// ws high-water ~42 MB (< proven-safe 57.9 MB).
// ---------------------------------------------------------------------------
extern "C" void kernel_launch(void* const* d_in, const int* in_sizes, int n_in,
                              void* d_out, int out_size, void* d_ws, size_t ws_size,
                              hipStream_t stream) {
    (void)in_sizes; (void)n_in; (void)out_size; (void)ws_size;

    char* ws = (char*)d_ws;
    size_t off = 0;
    auto alloc = [&](size_t bytes) {
        char* p = ws + off;
        off += (bytes + 255) & ~(size_t)255;
        return p;
    };

    unsigned short* xb    = (unsigned short*)alloc((size_t)B_ * N_ * C_ * 2);   // 16.78 MB
    unsigned short* qkwb  = (unsigned short*)alloc((size_t)2 * C_ * C_ * 2);    // 4.19 MB
    unsigned short* pwb   = (unsigned short*)alloc((size_t)C_ * C_ * 2);        // 2.10 MB
    unsigned short* pbb   = (unsigned short*)alloc((size_t)C_ * 2);
    unsigned short* we_i  = (unsigned short*)alloc((size_t)H_ * RS * LR * 2);
    unsigned short* wr_i  = (unsigned short*)alloc((size_t)H_ * RS * LR * 2);
    unsigned short* cwwb  = (unsigned short*)alloc((size_t)HD * 2 * LR * 2);
    unsigned short* cwbb  = (unsigned short*)alloc((size_t)HD * 2);
    unsigned short* attn  = (unsigned short*)alloc((size_t)B_ * N_ * C_ * 2);   // 16.78 MB
    unsigned short* we2t  = (unsigned short*)alloc((size_t)B_ * H_ * HD * HD * 2);
    unsigned short* wr2t  = (unsigned short*)alloc((size_t)B_ * H_ * HD * HD * 2);

    const int M = B_ * N_;  // 8192

    // 1) convert all inputs to bf16 copies (self-detecting dtype)
    CvtArgs ca;
    ca.src[0] = d_in[0]; ca.dst[0] = xb;   ca.size[0] = B_ * N_ * C_;
    ca.src[1] = d_in[1]; ca.dst[1] = qkwb; ca.size[1] = 2 * C_ * C_;
    ca.src[2] = d_in[2]; ca.dst[2] = pwb;  ca.size[2] = C_ * C_;
    ca.src[3] = d_in[3]; ca.dst[3] = pbb;  ca.size[3] = C_;
    ca.src[4] = d_in[4]; ca.dst[4] = we_i; ca.size[4] = H_ * RS * LR;
    ca.src[5] = d_in[5]; ca.dst[5] = wr_i; ca.size[5] = H_ * RS * LR;
    ca.src[6] = d_in[6]; ca.dst[6] = cwwb; ca.size[6] = HD * 2 * LR;
    ca.src[7] = d_in[7]; ca.dst[7] = cwbb; ca.size[7] = HD;
    convert_kernel<<<dim3(2048, 8), 256, 0, stream>>>(ca);

    // 2) fused gen_weights (gather + wec + collapse) -> We2T/Wr2T
    prep_kernel<<<B_ * H_, 256, 0, stream>>>(xb, we_i, wr_i, cwwb, we2t, wr2t);

    // 3) fused qk-projection + l2norm + score + cw projection -> attn
    gemm1_score_kernel<<<dim3(H_, M / 128), 256, 0, stream>>>(
        xb, qkwb, we2t, wr2t, cwbb, attn);

    // 4) output projection: out = attn @ proj_w^T + proj_b (self-detecting)
    gemm2_kernel<<<dim3(C_ / 128, M / 128), 256, 0, stream>>>(
        (const unsigned int*)d_in[0], attn, pwb, pbb, d_out);
}

// Round 9
// 209.618 us; speedup vs baseline: 1.2444x; 1.2444x over previous
//
#include <hip/hip_runtime.h>
#include <hip/hip_bf16.h>

// Problem shapes (fixed by setup_inputs)
constexpr int B_  = 4;
constexpr int N_  = 2048;
constexpr int C_  = 1024;
constexpr int H_  = 16;
constexpr int HD  = 64;    // head dim
constexpr int LR  = 20;    // low rank
constexpr int RS  = 200;   // subsample length R
constexpr int RP  = 224;   // RS padded to multiple of 32 (zero-filled)

typedef __attribute__((ext_vector_type(8))) short bf16x8;
typedef __attribute__((ext_vector_type(4))) float f32x4;

__device__ __forceinline__ float b2f_raw(unsigned short u) {
    union { unsigned int i; float f; } v;
    v.i = ((unsigned int)u) << 16;
    return v.f;
}
__device__ __forceinline__ unsigned short f2b(float f) {
    __hip_bfloat16 h = __float2bfloat16(f);
    return *(unsigned short*)&h;
}
template <bool BF>
__device__ __forceinline__ float ldg(const void* p, size_t i) {
    if constexpr (BF) return b2f_raw(((const unsigned short*)p)[i]);
    else              return ((const float*)p)[i];
}

// async 16B global->LDS (wave-uniform LDS base; HW scatters lane i at +16*i)
__device__ __forceinline__ void async_load16(const unsigned short* g, unsigned short* l) {
    __builtin_amdgcn_global_load_lds(
        (const __attribute__((address_space(1))) unsigned int*)(const void*)g,
        (__attribute__((address_space(3))) unsigned int*)(void*)l,
        16, 0, 0);
}

// ---------------------------------------------------------------------------
// dtype detection (single tiny kernel — proven cheap in rounds 2-7).
// ---------------------------------------------------------------------------
__global__ __launch_bounds__(256)
void detect_kernel(const unsigned int* __restrict__ x, int* __restrict__ flag) {
    const int t = threadIdx.x;
    int cnt = 0;
    for (int i = t; i < 1024; i += 256) {
        const unsigned int w = x[i];
        const unsigned int e = (w >> 7) & 0xFFu;
        cnt += (e >= 103u && e <= 140u) ? 1 : 0;
    }
    __shared__ int s[256];
    s[t] = cnt;
    __syncthreads();
    for (int off = 128; off > 0; off >>= 1) {
        if (t < off) s[t] += s[t + off];
        __syncthreads();
    }
    if (t == 0) *flag = (s[0] > 512) ? 1 : 0;  // 1 = bf16 inputs, 0 = fp32
}

// ---------------------------------------------------------------------------
// Fused convert + wec + gather. Grid (2048, 7):
//  y in [0,5): convert buffer y (x, qkw, proj_w, proj_b, cw_b) to bf16
//  y == 5:    wec from RAW we/wr/cw_w: wect[h][dout][r] = sum_e we*cw
//  y == 6:    gather from RAW x: xh[bh][din][r] = x[b, idx[r], h*64+din]
// idx[r] = (r*(N-1))/(R-1) exactly (trunc linspace); r zero-padded to 224.
// ---------------------------------------------------------------------------
struct CvtArgs {
    const void* src[5];
    unsigned short* dst[5];
    int size[5];
};

template <bool BF>
__device__ void wec_body(const void* __restrict__ we_raw,
                         const void* __restrict__ wr_raw,
                         const void* __restrict__ cw_raw,
                         unsigned short* __restrict__ wect,
                         unsigned short* __restrict__ wrct) {
    const int o = blockIdx.x * 256 + threadIdx.x;
    if (o >= H_ * HD * RP) return;
    const int r    = o % RP;
    const int dout = (o / RP) % HD;
    const int h    = o / (RP * HD);
    float sq = 0.f, sk = 0.f;
    if (r < RS) {
        #pragma unroll
        for (int e = 0; e < LR; ++e) {
            const float cq = ldg<BF>(cw_raw, dout * 2 * LR + e);
            const float ck = ldg<BF>(cw_raw, dout * 2 * LR + LR + e);
            sq += ldg<BF>(we_raw, ((size_t)h * RS + r) * LR + e) * cq;
            sk += ldg<BF>(wr_raw, ((size_t)h * RS + r) * LR + e) * ck;
        }
    }
    wect[o] = f2b(sq);
    wrct[o] = f2b(sk);
}

template <bool BF>
__device__ void gather_body(const void* __restrict__ x_raw,
                            unsigned short* __restrict__ xh) {
    const int bh = blockIdx.x;
    if (bh >= B_ * H_) return;
    const int b = bh >> 4;
    const int h = bh & 15;
    for (int o = threadIdx.x; o < HD * RP; o += 256) {
        const int din = o & 63;   // consecutive threads -> coalesced reads
        const int r   = o >> 6;
        unsigned short v = 0;
        if (r < RS) {
            const int ir = (r * (N_ - 1)) / (RS - 1);
            const size_t idx = ((size_t)b * N_ + ir) * C_ + h * HD + din;
            if constexpr (BF) v = ((const unsigned short*)x_raw)[idx];
            else              v = f2b(((const float*)x_raw)[idx]);
        }
        xh[(size_t)bh * HD * RP + (size_t)din * RP + r] = v;
    }
}

__global__ __launch_bounds__(256)
void fused_prep_kernel(const int* __restrict__ flag, CvtArgs args,
                       const void* __restrict__ we_raw,
                       const void* __restrict__ wr_raw,
                       const void* __restrict__ cw_raw,
                       unsigned short* __restrict__ wect,
                       unsigned short* __restrict__ wrct,
                       unsigned short* __restrict__ xh) {
    const bool isbf = (*flag != 0);
    const int y = blockIdx.y;
    if (y < 5) {
        const int n4 = args.size[y] >> 2;
        const int stride = gridDim.x * blockDim.x;
        for (int i = blockIdx.x * blockDim.x + threadIdx.x; i < n4; i += stride) {
            ushort4 o;
            if (isbf) {
                o = ((const ushort4*)args.src[y])[i];
            } else {
                const float4 v = ((const float4*)args.src[y])[i];
                o.x = f2b(v.x); o.y = f2b(v.y); o.z = f2b(v.z); o.w = f2b(v.w);
            }
            ((ushort4*)args.dst[y])[i] = o;
        }
    } else if (y == 5) {
        if (isbf) wec_body<true>(we_raw, wr_raw, cw_raw, wect, wrct);
        else      wec_body<false>(we_raw, wr_raw, cw_raw, wect, wrct);
    } else {
        if (isbf) gather_body<true>(args.src[0], xh);
        else      gather_body<false>(args.src[0], xh);
    }
}

// ---------------------------------------------------------------------------
// collapse: We2T[bh][dout][din] = sum_r wec[h][dout][r] * xh[bh][din][r]
// Tiny NT MFMA GEMM, M=N=64, K=224. One wave per (bh, qk-sel, dout-half).
// (verified in rounds 5-8)
// ---------------------------------------------------------------------------
__global__ __launch_bounds__(64)
void collapse_kernel(const unsigned short* __restrict__ xh,
                     const unsigned short* __restrict__ wect,
                     const unsigned short* __restrict__ wrct,
                     unsigned short* __restrict__ we2t,
                     unsigned short* __restrict__ wr2t) {
    const int blk = blockIdx.x;
    const int bh  = blk >> 2;
    const int qk  = (blk >> 1) & 1;
    const int dh  = blk & 1;
    const int h   = bh & 15;
    const int lane = threadIdx.x;
    const int lq = lane >> 4;
    const int lm = lane & 15;

    const unsigned short* wsrc = (qk ? wrct : wect) + (size_t)h * HD * RP;
    const unsigned short* xsrc = xh + (size_t)bh * HD * RP;
    unsigned short* dst = (qk ? wr2t : we2t) + (size_t)bh * HD * HD;

    f32x4 acc[2][4];
    #pragma unroll
    for (int i = 0; i < 2; ++i)
        #pragma unroll
        for (int j = 0; j < 4; ++j) acc[i][j] = 0.f;

    for (int ks = 0; ks < RP / 32; ++ks) {
        bf16x8 a[2], bfr[4];
        #pragma unroll
        for (int rt = 0; rt < 2; ++rt)
            a[rt] = *(const bf16x8*)&wsrc[(size_t)(dh * 32 + rt * 16 + lm) * RP + ks * 32 + lq * 8];
        #pragma unroll
        for (int j = 0; j < 4; ++j)
            bfr[j] = *(const bf16x8*)&xsrc[(size_t)(j * 16 + lm) * RP + ks * 32 + lq * 8];
        #pragma unroll
        for (int rt = 0; rt < 2; ++rt)
            #pragma unroll
            for (int j = 0; j < 4; ++j)
                acc[rt][j] = __builtin_amdgcn_mfma_f32_16x16x32_bf16(
                    a[rt], bfr[j], acc[rt][j], 0, 0, 0);
    }

    #pragma unroll
    for (int rt = 0; rt < 2; ++rt)
        #pragma unroll
        for (int j = 0; j < 4; ++j)
            #pragma unroll
            for (int r = 0; r < 4; ++r) {
                const int dout = dh * 32 + rt * 16 + lq * 4 + r;
                const int din  = j * 16 + lm;
                dst[dout * HD + din] = f2b(acc[rt][j][r]);
            }
}

// ---------------------------------------------------------------------------
// Fused gemm1 + l2norm + score. Phase 1 now BK=64 via TWO half-buffers per
// operand (each in the proven BK=32 layout -> bank pattern unchanged):
// halves the barrier count (16 iters instead of 32).
// ---------------------------------------------------------------------------
__global__ __launch_bounds__(256)
void gemm1_score_kernel(const unsigned short* __restrict__ xb,
                        const unsigned short* __restrict__ qkwb,
                        const unsigned short* __restrict__ we2t,
                        const unsigned short* __restrict__ wr2t,
                        const unsigned short* __restrict__ cwbb,
                        unsigned short* __restrict__ attn) {
    constexpr int QS = 72;
    __shared__ __align__(16) unsigned short pool[2 * 128 * QS];  // 36 KB
    unsigned short* As0 = pool;                 // 128x32
    unsigned short* As1 = pool + 4096;
    unsigned short* Bs0 = pool + 8192;
    unsigned short* Bs1 = pool + 12288;
    unsigned short* qn  = pool;                 // phase 2: 128xQS
    unsigned short* kn  = pool + 128 * QS;

    const int t    = threadIdx.x;
    const int wave = t >> 6;
    const int lane = t & 63;
    const int h    = blockIdx.x;
    const int m0   = blockIdx.y * 128;
    const int K    = C_;

    const int srow = lane >> 2;
    const int scol = (lane & 3) * 8;
    const unsigned short* ga0 = xb + (size_t)(m0 + wave * 16 + srow) * K + scol;
    const unsigned short* ga1 = xb + (size_t)(m0 + (wave + 4) * 16 + srow) * K + scol;
    const unsigned short* gb0 = qkwb + (size_t)(h * HD + wave * 16 + srow) * K + scol;
    const unsigned short* gb1 = qkwb + (size_t)(C_ + h * HD + wave * 16 + srow) * K + scol;
    unsigned short* lAa = &As0[wave * 512];
    unsigned short* lAb = &As0[(wave + 4) * 512];
    unsigned short* lBa = &Bs0[wave * 512];
    unsigned short* lBb = &Bs0[(wave + 4) * 512];
    unsigned short* lAa1 = &As1[wave * 512];
    unsigned short* lAb1 = &As1[(wave + 4) * 512];
    unsigned short* lBa1 = &Bs1[wave * 512];
    unsigned short* lBb1 = &Bs1[(wave + 4) * 512];

    const int wr = (wave >> 1) * 64;        // row quadrant
    const int wc = (wave & 1) * 64;         // col quadrant: 0 = q, 64 = k
    const int lq = lane >> 4;
    const int lm = lane & 15;

    f32x4 acc[4][4];
    #pragma unroll
    for (int i = 0; i < 4; ++i)
        #pragma unroll
        for (int j = 0; j < 4; ++j) acc[i][j] = 0.f;

    for (int k0 = 0; k0 < K; k0 += 64) {
        async_load16(ga0, lAa);  async_load16(ga0 + 32, lAa1);
        async_load16(ga1, lAb);  async_load16(ga1 + 32, lAb1);
        async_load16(gb0, lBa);  async_load16(gb0 + 32, lBa1);
        async_load16(gb1, lBb);  async_load16(gb1 + 32, lBb1);
        ga0 += 64; ga1 += 64; gb0 += 64; gb1 += 64;
        __syncthreads();

        #pragma unroll
        for (int h2 = 0; h2 < 2; ++h2) {
            const unsigned short* As = h2 ? As1 : As0;
            const unsigned short* Bs = h2 ? Bs1 : Bs0;
            bf16x8 af[4], bfr[4];
            #pragma unroll
            for (int i = 0; i < 4; ++i)
                af[i] = *(const bf16x8*)&As[(wr + i * 16 + lm) * 32 + lq * 8];
            #pragma unroll
            for (int j = 0; j < 4; ++j)
                bfr[j] = *(const bf16x8*)&Bs[(wc + j * 16 + lm) * 32 + lq * 8];
            #pragma unroll
            for (int i = 0; i < 4; ++i)
                #pragma unroll
                for (int j = 0; j < 4; ++j)
                    acc[i][j] = __builtin_amdgcn_mfma_f32_16x16x32_bf16(
                        af[i], bfr[j], acc[i][j], 0, 0, 0);
        }
        __syncthreads();
    }

    // ---- phase 2a: per-row l2 norm + scaled bf16 store to LDS ----
    unsigned short* dst = (wc == 0) ? qn : kn;
    #pragma unroll
    for (int i = 0; i < 4; ++i) {
        float inv[4];
        #pragma unroll
        for (int r = 0; r < 4; ++r) {
            float s = 0.f;
            #pragma unroll
            for (int j = 0; j < 4; ++j) s += acc[i][j][r] * acc[i][j][r];
            s += __shfl_xor(s, 1, 64);
            s += __shfl_xor(s, 2, 64);
            s += __shfl_xor(s, 4, 64);
            s += __shfl_xor(s, 8, 64);
            inv[r] = 1.f / fmaxf(sqrtf(s), 1e-12f);
        }
        #pragma unroll
        for (int j = 0; j < 4; ++j)
            #pragma unroll
            for (int r = 0; r < 4; ++r) {
                const int row = wr + i * 16 + lq * 4 + r;
                dst[row * QS + j * 16 + lm] = f2b(acc[i][j][r] * inv[r]);
            }
    }
    __syncthreads();

    // ---- phase 2b: attn = qn@We2T^T + kn@Wr2T^T + cw_b ----
    const int b  = blockIdx.y >> 4;
    const int bh = b * H_ + h;
    const unsigned short* wq = we2t + (size_t)bh * HD * HD;
    const unsigned short* wk = wr2t + (size_t)bh * HD * HD;

    bf16x8 bq[2][4], bk[2][4];
    #pragma unroll
    for (int t2 = 0; t2 < 2; ++t2)
        #pragma unroll
        for (int j = 0; j < 4; ++j) {
            const int dout = j * 16 + lm;
            bq[t2][j] = *(const bf16x8*)&wq[dout * HD + t2 * 32 + lq * 8];
            bk[t2][j] = *(const bf16x8*)&wk[dout * HD + t2 * 32 + lq * 8];
        }

    f32x4 accS[2][4];
    #pragma unroll
    for (int rt = 0; rt < 2; ++rt)
        #pragma unroll
        for (int j = 0; j < 4; ++j) accS[rt][j] = 0.f;

    #pragma unroll
    for (int rt = 0; rt < 2; ++rt) {
        const int lr = wave * 32 + rt * 16 + lm;
        bf16x8 aq0 = *(const bf16x8*)&qn[lr * QS + lq * 8];
        bf16x8 aq1 = *(const bf16x8*)&qn[lr * QS + 32 + lq * 8];
        bf16x8 ak0 = *(const bf16x8*)&kn[lr * QS + lq * 8];
        bf16x8 ak1 = *(const bf16x8*)&kn[lr * QS + 32 + lq * 8];
        #pragma unroll
        for (int j = 0; j < 4; ++j) {
            accS[rt][j] = __builtin_amdgcn_mfma_f32_16x16x32_bf16(aq0, bq[0][j], accS[rt][j], 0, 0, 0);
            accS[rt][j] = __builtin_amdgcn_mfma_f32_16x16x32_bf16(aq1, bq[1][j], accS[rt][j], 0, 0, 0);
            accS[rt][j] = __builtin_amdgcn_mfma_f32_16x16x32_bf16(ak0, bk[0][j], accS[rt][j], 0, 0, 0);
            accS[rt][j] = __builtin_amdgcn_mfma_f32_16x16x32_bf16(ak1, bk[1][j], accS[rt][j], 0, 0, 0);
        }
    }

    #pragma unroll
    for (int rt = 0; rt < 2; ++rt)
        #pragma unroll
        for (int j = 0; j < 4; ++j) {
            const int dout = j * 16 + lm;
            const float bv = b2f_raw(cwbb[dout]);
            #pragma unroll
            for (int r = 0; r < 4; ++r) {
                const int row = m0 + wave * 32 + rt * 16 + lq * 4 + r;
                attn[(size_t)row * C_ + h * HD + dout] = f2b(accS[rt][j][r] + bv);
            }
        }
}

// ---------------------------------------------------------------------------
// Output projection, BK=64 via split half-buffers. Flag selects output dtype.
// ---------------------------------------------------------------------------
template <bool OBF>
__device__ void mfma_gemm_body64(const unsigned short* __restrict__ A,
                                 const unsigned short* __restrict__ W,
                                 const unsigned short* __restrict__ bias,
                                 void* __restrict__ out,
                                 int M, int N, int K) {
    __shared__ __align__(16) unsigned short As0[4096], As1[4096];
    __shared__ __align__(16) unsigned short Bs0[4096], Bs1[4096];   // 32 KB

    const int t    = threadIdx.x;
    const int wave = t >> 6;
    const int lane = t & 63;
    const int m0   = blockIdx.y * 128;
    const int n0   = blockIdx.x * 128;

    const int srow = lane >> 2;
    const int scol = (lane & 3) * 8;
    const unsigned short* ga0 = A + (size_t)(m0 + wave * 16 + srow) * K + scol;
    const unsigned short* ga1 = A + (size_t)(m0 + (wave + 4) * 16 + srow) * K + scol;
    const unsigned short* gb0 = W + (size_t)(n0 + wave * 16 + srow) * K + scol;
    const unsigned short* gb1 = W + (size_t)(n0 + (wave + 4) * 16 + srow) * K + scol;
    unsigned short* lAa  = &As0[wave * 512];
    unsigned short* lAb  = &As0[(wave + 4) * 512];
    unsigned short* lBa  = &Bs0[wave * 512];
    unsigned short* lBb  = &Bs0[(wave + 4) * 512];
    unsigned short* lAa1 = &As1[wave * 512];
    unsigned short* lAb1 = &As1[(wave + 4) * 512];
    unsigned short* lBa1 = &Bs1[wave * 512];
    unsigned short* lBb1 = &Bs1[(wave + 4) * 512];

    const int wr = (wave >> 1) * 64;
    const int wc = (wave & 1) * 64;
    const int lq = lane >> 4;
    const int lm = lane & 15;

    f32x4 acc[4][4];
    #pragma unroll
    for (int i = 0; i < 4; ++i)
        #pragma unroll
        for (int j = 0; j < 4; ++j) acc[i][j] = 0.f;

    for (int k0 = 0; k0 < K; k0 += 64) {
        async_load16(ga0, lAa);  async_load16(ga0 + 32, lAa1);
        async_load16(ga1, lAb);  async_load16(ga1 + 32, lAb1);
        async_load16(gb0, lBa);  async_load16(gb0 + 32, lBa1);
        async_load16(gb1, lBb);  async_load16(gb1 + 32, lBb1);
        ga0 += 64; ga1 += 64; gb0 += 64; gb1 += 64;
        __syncthreads();

        #pragma unroll
        for (int h2 = 0; h2 < 2; ++h2) {
            const unsigned short* As = h2 ? As1 : As0;
            const unsigned short* Bs = h2 ? Bs1 : Bs0;
            bf16x8 af[4], bfr[4];
            #pragma unroll
            for (int i = 0; i < 4; ++i)
                af[i] = *(const bf16x8*)&As[(wr + i * 16 + lm) * 32 + lq * 8];
            #pragma unroll
            for (int j = 0; j < 4; ++j)
                bfr[j] = *(const bf16x8*)&Bs[(wc + j * 16 + lm) * 32 + lq * 8];
            #pragma unroll
            for (int i = 0; i < 4; ++i)
                #pragma unroll
                for (int j = 0; j < 4; ++j)
                    acc[i][j] = __builtin_amdgcn_mfma_f32_16x16x32_bf16(
                        af[i], bfr[j], acc[i][j], 0, 0, 0);
        }
        __syncthreads();
    }

    #pragma unroll
    for (int i = 0; i < 4; ++i) {
        #pragma unroll
        for (int j = 0; j < 4; ++j) {
            const int col = n0 + wc + j * 16 + lm;
            const float bv = b2f_raw(bias[col]);
            #pragma unroll
            for (int r = 0; r < 4; ++r) {
                const int row = m0 + wr + i * 16 + lq * 4 + r;
                const float v = acc[i][j][r] + bv;
                if constexpr (OBF)
                    ((__hip_bfloat16*)out)[(size_t)row * N + col] = __float2bfloat16(v);
                else
                    ((float*)out)[(size_t)row * N + col] = v;
            }
        }
    }
}

__global__ __launch_bounds__(256)
void gemm2_kernel(const int* __restrict__ flag,
                  const unsigned short* __restrict__ attn,
                  const unsigned short* __restrict__ pwb,
                  const unsigned short* __restrict__ pbb,
                  void* __restrict__ out) {
    if (*flag) mfma_gemm_body64<true>(attn, pwb, pbb, out, B_ * N_, C_, C_);
    else       mfma_gemm_body64<false>(attn, pwb, pbb, out, B_ * N_, C_, C_);
}

// ---------------------------------------------------------------------------
// 5 dispatches: detect -> fused(convert+wec+gather) -> collapse ->
// gemm1_score -> gemm2. ws high-water ~44 MB (< proven-safe 57.9 MB).
// ---------------------------------------------------------------------------
extern "C" void kernel_launch(void* const* d_in, const int* in_sizes, int n_in,
                              void* d_out, int out_size, void* d_ws, size_t ws_size,
                              hipStream_t stream) {
    (void)in_sizes; (void)n_in; (void)out_size; (void)ws_size;

    char* ws = (char*)d_ws;
    size_t off = 0;
    auto alloc = [&](size_t bytes) {
        char* p = ws + off;
        off += (bytes + 255) & ~(size_t)255;
        return p;
    };

    int* flag = (int*)alloc(16);
    unsigned short* xb    = (unsigned short*)alloc((size_t)B_ * N_ * C_ * 2);   // 16.78 MB
    unsigned short* qkwb  = (unsigned short*)alloc((size_t)2 * C_ * C_ * 2);    // 4.19 MB
    unsigned short* pwb   = (unsigned short*)alloc((size_t)C_ * C_ * 2);        // 2.10 MB
    unsigned short* pbb   = (unsigned short*)alloc((size_t)C_ * 2);
    unsigned short* cwbb  = (unsigned short*)alloc((size_t)HD * 2);
    unsigned short* attn  = (unsigned short*)alloc((size_t)B_ * N_ * C_ * 2);   // 16.78 MB
    unsigned short* we2t  = (unsigned short*)alloc((size_t)B_ * H_ * HD * HD * 2);
    unsigned short* wr2t  = (unsigned short*)alloc((size_t)B_ * H_ * HD * HD * 2);
    unsigned short* wect  = (unsigned short*)alloc((size_t)H_ * HD * RP * 2);
    unsigned short* wrct  = (unsigned short*)alloc((size_t)H_ * HD * RP * 2);
    unsigned short* xh    = (unsigned short*)alloc((size_t)B_ * H_ * HD * RP * 2);

    const int M = B_ * N_;  // 8192

    // 1) dtype detection
    detect_kernel<<<1, 256, 0, stream>>>((const unsigned int*)d_in[0], flag);

    // 2) fused convert (x, qk_w, proj_w, proj_b, cw_b) + wec + gather
    CvtArgs ca;
    ca.src[0] = d_in[0]; ca.dst[0] = xb;   ca.size[0] = B_ * N_ * C_;
    ca.src[1] = d_in[1]; ca.dst[1] = qkwb; ca.size[1] = 2 * C_ * C_;
    ca.src[2] = d_in[2]; ca.dst[2] = pwb;  ca.size[2] = C_ * C_;
    ca.src[3] = d_in[3]; ca.dst[3] = pbb;  ca.size[3] = C_;
    ca.src[4] = d_in[7]; ca.dst[4] = cwbb; ca.size[4] = HD;
    fused_prep_kernel<<<dim3(2048, 7), 256, 0, stream>>>(
        flag, ca, d_in[4], d_in[5], d_in[6], wect, wrct, xh);

    // 3) collapse -> We2T/Wr2T
    collapse_kernel<<<B_ * H_ * 4, 64, 0, stream>>>(xh, wect, wrct, we2t, wr2t);

    // 4) fused qk-projection + l2norm + score -> attn
    gemm1_score_kernel<<<dim3(H_, M / 128), 256, 0, stream>>>(
        xb, qkwb, we2t, wr2t, cwbb, attn);

    // 5) output projection: out = attn @ proj_w^T + proj_b
    gemm2_kernel<<<dim3(C_ / 128, M / 128), 256, 0, stream>>>(
        flag, attn, pwb, pbb, d_out);
}